// Round 1
// baseline (185.788 us; speedup 1.0000x reference)
//
#include <hip/hip_runtime.h>
#include <hip/hip_bf16.h>

// Head: out[b,t,h] = softmax_causal( (x@Wq)(x@Wk)^T * 6^-0.5 ) @ (x@Wv)
// B=512 T=128 C=384 H=64. One block per b, bf16 MFMA 16x16x32.
//
// V2: barrier-free phase 1.
//  - pre-kernel build_wt converts W -> bf16 W^T in exact MFMA B-fragment order
//    into d_ws (147456 B needed). B-fragments load straight from global
//    (coalesced 16B/lane, identical across waves -> L1 broadcast).
//  - A-fragments (x) double-buffered in registers, prefetched 1 chunk ahead.
//  - No Ws staging, no barriers in phase 1 (was 24 barriers/block).
//  - LDS 64.5KB -> 48KB.

#define B_ 512
#define T_ 128
#define C_ 384
#define H_ 64

typedef __bf16 bf16;
typedef __attribute__((ext_vector_type(8))) __bf16 bf16x8;
typedef __attribute__((ext_vector_type(4))) __bf16 bf16x4;
typedef __attribute__((ext_vector_type(4))) float f32x4;

// ---------------- pre-kernel: W -> bf16 W^T in MFMA B-fragment order --------
// Wt[((kc*12 + tn)*64 + lane)*8 + e] = Wsel[(kc*32 + quad*8 + e)*64 + h]
//   lane = quad*16+lm, n = tn*16+lm, j = n>>6 selects Wq/Wk/Wv, h = n&63.
__global__ void build_wt(const float* __restrict__ Wq, const float* __restrict__ Wk,
                         const float* __restrict__ Wv, bf16* __restrict__ Wt)
{
    int t = blockIdx.x * 256 + threadIdx.x;   // 9216 threads total
    if (t >= 12 * 12 * 64) return;
    int lane = t & 63;
    int tn   = (t >> 6) % 12;
    int kc   = t / (12 * 64);
    int lm = lane & 15, quad = lane >> 4;
    int n = tn * 16 + lm;
    int j = n >> 6, h = n & 63;
    const float* Wp = (j == 0) ? Wq : (j == 1) ? Wk : Wv;
    int k0 = kc * 32 + quad * 8;
    bf16x8 v;
#pragma unroll
    for (int e = 0; e < 8; ++e) v[e] = (bf16)Wp[(k0 + e) * H_ + h];
    *(bf16x8*)&Wt[t * 8] = v;
}

// LDS element offsets (bf16):
//  Qs  [0,8192)      : 128 x 64, XOR-swizzled units of 8
//  Ks  [8192,16384)  : 128 x 64, swizzled
//  Vts [16384,24576) : 64 x 128 (V^T), swizzled
//  Ps  aliases [0,16384) : 128 x 128, swizzled  (after barrier)
// total 49152 bytes

__launch_bounds__(256, 2)
__global__ void head_fused(const float* __restrict__ x,
                           const bf16* __restrict__ Wt,
                           float* __restrict__ out)
{
    __shared__ bf16 lds[24576];
    bf16* Qs  = lds;
    bf16* Ks  = lds + 8192;
    bf16* Vts = lds + 16384;
    bf16* Ps  = lds;            // aliases Qs+Ks after barrier

    const int tid  = threadIdx.x;
    const int w    = tid >> 6;     // wave 0..3
    const int lane = tid & 63;
    const int lm   = lane & 15;    // fragment row/col index
    const int quad = lane >> 4;    // fragment k-group / row-group
    const int b    = blockIdx.x;

    const float* xb = x + (size_t)b * (T_ * C_);

    // ================= Phase 1: QKV = x[b] @ [Wq|Wk|Wv] =================
    // wave w owns m rows [32w, 32w+32), all 192 n columns. No LDS, no barriers.
    f32x4 acc[2][12];
#pragma unroll
    for (int i = 0; i < 2; ++i)
#pragma unroll
        for (int t = 0; t < 12; ++t) acc[i][t] = (f32x4){0.f, 0.f, 0.f, 0.f};

    const float* xr0 = xb + (32 * w + lm) * C_ + quad * 8;        // i=0 row
    const float* xr1 = xb + (32 * w + 16 + lm) * C_ + quad * 8;   // i=1 row
    const bf16*  wl  = Wt + lane * 8;

    float4 xA[4], xB[4];   // [i*2+half], constant-indexed only -> registers

    auto LD = [&](int kc, float4* xr) {
        xr[0] = *(const float4*)(xr0 + kc * 32);
        xr[1] = *(const float4*)(xr0 + kc * 32 + 4);
        xr[2] = *(const float4*)(xr1 + kc * 32);
        xr[3] = *(const float4*)(xr1 + kc * 32 + 4);
    };
    auto CHUNK = [&](int kc, const float4* xr) {
        bf16x8 a0 = {(bf16)xr[0].x, (bf16)xr[0].y, (bf16)xr[0].z, (bf16)xr[0].w,
                     (bf16)xr[1].x, (bf16)xr[1].y, (bf16)xr[1].z, (bf16)xr[1].w};
        bf16x8 a1 = {(bf16)xr[2].x, (bf16)xr[2].y, (bf16)xr[2].z, (bf16)xr[2].w,
                     (bf16)xr[3].x, (bf16)xr[3].y, (bf16)xr[3].z, (bf16)xr[3].w};
        const bf16* wp = wl + kc * 6144;
#pragma unroll
        for (int tn = 0; tn < 12; ++tn) {
            bf16x8 bfr = *(const bf16x8*)(wp + tn * 512);
            acc[0][tn] = __builtin_amdgcn_mfma_f32_16x16x32_bf16(a0, bfr, acc[0][tn], 0, 0, 0);
            acc[1][tn] = __builtin_amdgcn_mfma_f32_16x16x32_bf16(a1, bfr, acc[1][tn], 0, 0, 0);
        }
    };

    LD(0, xA);
#pragma unroll
    for (int kc = 0; kc < 12; kc += 2) {
        LD(kc + 1, xB);
        CHUNK(kc, xA);
        if (kc + 2 < 12) LD(kc + 2, xA);
        CHUNK(kc + 1, xB);
    }

    // epilogue: Q,K row-major [t][h]; V transposed [h][t]; all swizzled bf16
#pragma unroll
    for (int i = 0; i < 2; ++i) {
#pragma unroll
        for (int tn = 0; tn < 12; ++tn) {
            int gn = 16 * tn + lm;
            int j = gn >> 6, h = gn & 63;
            int m0 = 32 * w + 16 * i + quad * 4;
            if (j == 2) {
                bf16x4 v4 = {(bf16)acc[i][tn][0], (bf16)acc[i][tn][1],
                             (bf16)acc[i][tn][2], (bf16)acc[i][tn][3]};
                int pc = (m0 & 7) | ((((m0 >> 3) ^ (h & 15)) & 15) << 3);
                *(bf16x4*)&Vts[h * 128 + pc] = v4;
            } else {
                bf16* dst = (j == 0) ? Qs : Ks;
#pragma unroll
                for (int r = 0; r < 4; ++r) {
                    int m = m0 + r;
                    int pc = (h & 7) | ((((h >> 3) ^ (m & 7)) & 7) << 3);
                    dst[m * 64 + pc] = (bf16)acc[i][tn][r];
                }
            }
        }
    }
    __syncthreads();

    // ================= Phase 2: attention =================
    const float SCALE = 0.40824829046386307f;  // 6^-0.5
    const int tmg0 = w, tmg1 = 7 - w;          // balanced: (w+1)+(8-w)=9 tiles/wave

    f32x4 sacc[2][8];
#pragma unroll
    for (int i = 0; i < 2; ++i)
#pragma unroll
        for (int t = 0; t < 8; ++t) sacc[i][t] = (f32x4){0.f, 0.f, 0.f, 0.f};

    // S = Q K^T  (skip fully-masked tiles)
#pragma unroll
    for (int i = 0; i < 2; ++i) {
        const int tm = i ? tmg1 : tmg0;
        const int mrow = 16 * tm + lm;
        bf16x8 qa[2];
#pragma unroll
        for (int ks = 0; ks < 2; ++ks) {
            int phys = ((ks * 4 + quad) ^ (mrow & 7)) & 7;
            qa[ks] = *(const bf16x8*)&Qs[mrow * 64 + phys * 8];
        }
#pragma unroll
        for (int tn = 0; tn < 8; ++tn) {
            if (tn <= tm) {
                int nrow = 16 * tn + lm;
#pragma unroll
                for (int ks = 0; ks < 2; ++ks) {
                    int phys = ((ks * 4 + quad) ^ (nrow & 7)) & 7;
                    bf16x8 kb = *(const bf16x8*)&Ks[nrow * 64 + phys * 8];
                    sacc[i][tn] =
                        __builtin_amdgcn_mfma_f32_16x16x32_bf16(qa[ks], kb, sacc[i][tn], 0, 0, 0);
                }
            }
        }
    }

    // softmax, fully in registers; rows live in contiguous 16-lane groups
#pragma unroll
    for (int i = 0; i < 2; ++i) {
        const int tm = i ? tmg1 : tmg0;
#pragma unroll
        for (int r = 0; r < 4; ++r) {
            int m = 16 * tm + quad * 4 + r;
            float mx = -1e30f;
#pragma unroll
            for (int tn = 0; tn < 8; ++tn) {
                if (tn <= tm) {
                    int n = 16 * tn + lm;
                    float v = (n <= m) ? sacc[i][tn][r] * SCALE : -1e30f;
                    sacc[i][tn][r] = v;
                    mx = fmaxf(mx, v);
                }
            }
#pragma unroll
            for (int off = 1; off < 16; off <<= 1) mx = fmaxf(mx, __shfl_xor(mx, off, 16));
            float sum = 0.f;
#pragma unroll
            for (int tn = 0; tn < 8; ++tn) {
                if (tn <= tm) {
                    float e = __expf(sacc[i][tn][r] - mx);
                    sacc[i][tn][r] = e;
                    sum += e;
                }
            }
#pragma unroll
            for (int off = 1; off < 16; off <<= 1) sum += __shfl_xor(sum, off, 16);
            float inv = 1.f / sum;
#pragma unroll
            for (int tn = 0; tn < 8; ++tn) {
                if (tn <= tm) sacc[i][tn][r] *= inv;
            }
        }
    }

    __syncthreads();  // everyone done reading Qs/Ks; Ps aliases them

    // write P (bf16, swizzled). Each wave writes only its own rows.
#pragma unroll
    for (int i = 0; i < 2; ++i) {
        const int tm = i ? tmg1 : tmg0;
#pragma unroll
        for (int tn = 0; tn < 8; ++tn) {
            if (tn <= tm) {
                int n = 16 * tn + lm;
#pragma unroll
                for (int r = 0; r < 4; ++r) {
                    int m = 16 * tm + quad * 4 + r;
                    int pc = (n & 7) | ((((n >> 3) ^ (m & 15)) & 15) << 3);
                    Ps[m * 128 + pc] = (bf16)sacc[i][tn][r];
                }
            }
        }
        if ((tm & 1) == 0) {  // zero the half-covered k-tile (tm even)
            int m = 16 * tm + lm;
            int c0 = 16 * (tm + 1) + quad * 4;
            int pc = (c0 & 7) | ((((c0 >> 3) ^ (m & 15)) & 15) << 3);
            *(bf16x4*)&Ps[m * 128 + pc] =
                (bf16x4){(bf16)0.f, (bf16)0.f, (bf16)0.f, (bf16)0.f};
        }
    }

    // O = P @ V  (k-tiles limited by causal extent; reads only own P rows)
    f32x4 oacc[2][4];
#pragma unroll
    for (int i = 0; i < 2; ++i)
#pragma unroll
        for (int t = 0; t < 4; ++t) oacc[i][t] = (f32x4){0.f, 0.f, 0.f, 0.f};

#pragma unroll
    for (int i = 0; i < 2; ++i) {
        const int tm = i ? tmg1 : tmg0;
        const int mrow = 16 * tm + lm;
        const int nks = (tm + 2) >> 1;
        for (int ks = 0; ks < nks; ++ks) {  // wave-uniform bound
            int unit = ks * 4 + quad;
            int phys = (unit ^ (mrow & 15)) & 15;
            bf16x8 pa = *(const bf16x8*)&Ps[mrow * 128 + phys * 8];
#pragma unroll
            for (int th = 0; th < 4; ++th) {
                int hrow = 16 * th + lm;
                int ph2 = (unit ^ (hrow & 15)) & 15;
                bf16x8 vb = *(const bf16x8*)&Vts[hrow * 128 + ph2 * 8];
                oacc[i][th] =
                    __builtin_amdgcn_mfma_f32_16x16x32_bf16(pa, vb, oacc[i][th], 0, 0, 0);
            }
        }
    }

    // store O fp32 [b][t][h]
    float* ob = out + (size_t)b * (T_ * H_);
#pragma unroll
    for (int i = 0; i < 2; ++i) {
        const int tm = i ? tmg1 : tmg0;
#pragma unroll
        for (int th = 0; th < 4; ++th) {
            int h = 16 * th + lm;
#pragma unroll
            for (int r = 0; r < 4; ++r) {
                int m = 16 * tm + quad * 4 + r;
                ob[m * 64 + h] = oacc[i][th][r];
            }
        }
    }
}

extern "C" void kernel_launch(void* const* d_in, const int* in_sizes, int n_in,
                              void* d_out, int out_size, void* d_ws, size_t ws_size,
                              hipStream_t stream) {
    const float* x  = (const float*)d_in[0];
    const float* Wq = (const float*)d_in[1];
    const float* Wk = (const float*)d_in[2];
    const float* Wv = (const float*)d_in[3];
    float* o = (float*)d_out;
    bf16* Wt = (bf16*)d_ws;   // needs 147456 bytes
    build_wt<<<dim3(36), dim3(256), 0, stream>>>(Wq, Wk, Wv, Wt);
    head_fused<<<dim3(B_), dim3(256), 0, stream>>>(x, Wt, o);
}